// Round 12
// baseline (432.480 us; speedup 1.0000x reference)
//
#include <hip/hip_runtime.h>
#include <hip/hip_bf16.h>
#include <stdint.h>

#define IN_CH 64
#define OUT_CH 128

typedef __bf16 bf16x8 __attribute__((ext_vector_type(8)));
typedef float  f32x4  __attribute__((ext_vector_type(4)));

__device__ inline unsigned short f2bf(float f) {
    unsigned u = __float_as_uint(f);
    unsigned r = (u + 0x7fffu + ((u >> 16) & 1u)) >> 16;
    return (unsigned short)r;
}

// ---------- fast path ----------

// One prep kernel, three block-ranges:
//  [0, invBlocks)                : inv[] = zero_row; sums = 0
//  [invBlocks, invBlocks+cvtB)   : feats fp32 -> bf16 (+1 zero row)
//  [invBlocks+cvtB, ...)         : W -> wsw, bf16 in MFMA-A fragment order:
//     wsw[((k*16 + g*2 + h)*64 + lane)*8 + j] = bf16(W[k][h*32+(lane>>4)*8+j][g*16+(lane&15)])
__global__ void __launch_bounds__(256) prep_kernel(
    int* __restrict__ inv, int invTot, int zero_row, float* __restrict__ sums,
    const float4* __restrict__ f4, ushort* __restrict__ fb, int n4,
    const float* __restrict__ W, ushort* __restrict__ wsw,
    int invBlocks, int cvtBlocks)
{
    const int b = blockIdx.x;
    const int t = threadIdx.x;
    if (b < invBlocks) {
        int i = b * 256 + t;
        if (i < invTot) inv[i] = zero_row;
        if (b == 0) sums[t] = 0.f;
    } else if (b < invBlocks + cvtBlocks) {
        int i = (b - invBlocks) * 256 + t;
        if (i < n4 + 16) {
            ushort4 o;
            if (i < n4) {
                float4 v = f4[i];
                o.x = f2bf(v.x); o.y = f2bf(v.y); o.z = f2bf(v.z); o.w = f2bf(v.w);
            } else {
                o.x = 0; o.y = 0; o.z = 0; o.w = 0;   // zero row for absent entries
            }
            ((ushort4*)fb)[i] = o;
        }
    } else {
        int i = (b - invBlocks - cvtBlocks) * 256 + t;  // one thread = one fragment chunk
        if (i < 9 * 16 * 64) {
            int lane = i & 63;
            int gh = (i >> 6) & 15;
            int k = i >> 10;
            int half = gh & 1;
            int g = gh >> 1;
            int ch = g * 16 + (lane & 15);
            int in0 = half * 32 + (lane >> 4) * 8;
            ushort v[8];
#pragma unroll
            for (int j = 0; j < 8; ++j)
                v[j] = f2bf(W[((size_t)k * IN_CH + in0 + j) * OUT_CH + ch]);
            *(ushort4*)(wsw + (size_t)i * 8)     = make_ushort4(v[0], v[1], v[2], v[3]);
            *(ushort4*)(wsw + (size_t)i * 8 + 4) = make_ushort4(v[4], v[5], v[6], v[7]);
        }
    }
}

// Inverse rulebook, atomic-free: for fixed k the in->out map of a strided
// conv is injective, so inv[out*9+k] has exactly one writer.
__global__ void __launch_bounds__(256) build_inv_kernel(
    const int* __restrict__ in_idx,
    const int* __restrict__ out_idx,
    const int* __restrict__ mask,
    int* __restrict__ inv,
    int R)
{
    int r = blockIdx.x * 256 + threadIdx.x;
    if (r >= R) return;
    int k = blockIdx.y;
    size_t e = (size_t)k * R + r;
    if (!mask[e]) return;
    inv[(size_t)out_idx[e] * 9 + k] = in_idx[e];
}

// Fused: out[e] = sum_k W[k]^T . fb[inv[e][k]], + fused BN-stat partials.
// 8 waves / 256 contiguous entries per block (locality load-bearing, r10).
// Verified r4/r8/r11 sync skeleton: W tiles reg-staged into 2x16KB LDS
// double-buffer, backend-managed vmcnt, raw s_barrier, depth-1 F prefetch.
// r12 changes: (a) staging split into two lane-stride-16B streams (r11's
// 32B-stride pattern was a 16-way LDS bank conflict, 1.68M hits);
// (b) epilogue writes out via LDS transpose so every global store covers
// full 128B lines (was 16B/lane at 64B stride -> 1.9x write amplification).
__global__ void __launch_bounds__(512, 3) fused_out_kernel(
    const ushort* __restrict__ fb,    // [N_in+1][64] bf16 (last row zeros)
    const ushort* __restrict__ wsw,   // [9][16][64][8] bf16 fragment-order
    const int* __restrict__ inv,      // [n_out][9]
    float* __restrict__ out,          // [n_out][128] fp32
    float* __restrict__ sums,         // [256]
    int n_out, int zero_row)
{
    __shared__ __align__(16) char smraw[40960];
    // loop phase: [0,32768) = 2 x 16KB W tiles; [32768,40960) = redS/redQ
    // epilogue:   [0,33792) = [64][132]-float transpose buffer
    ushort (*ldsW)[8192] = (ushort(*)[8192])smraw;
    float* redS = (float*)(smraw + 32768);            // [8][128]
    float* redQ = (float*)(smraw + 36864);            // [8][128]

    const int lane = threadIdx.x & 63;
    const int w = threadIdx.x >> 6;            // 0..7
    const int col = lane & 15;
    const int quad = lane >> 4;
    const int base = blockIdx.x * 256 + w * 32;
    const int eA = base + col;
    const int eB = base + 16 + col;
    const bool okA = eA < n_out;
    const bool okB = eB < n_out;

    int ivA[9], ivB[9];
    {
        const int* __restrict__ pA = inv + (size_t)(okA ? eA : 0) * 9;
        const int* __restrict__ pB = inv + (size_t)(okB ? eB : 0) * 9;
#pragma unroll
        for (int k = 0; k < 9; ++k) ivA[k] = okA ? pA[k] : zero_row;
#pragma unroll
        for (int k = 0; k < 9; ++k) ivB[k] = okB ? pB[k] : zero_row;
    }

    // Wave stages 2KB/tile as TWO lane-stride-16B streams (conflict-free).
    const int s0 = w * 2048 + lane * 16;       // first KB
    const int s1 = s0 + 1024;                  // second KB

    f32x4 accA[8], accB[8];
#pragma unroll
    for (int g = 0; g < 8; ++g) {
        accA[g] = (f32x4){0.f, 0.f, 0.f, 0.f};
        accB[g] = (f32x4){0.f, 0.f, 0.f, 0.f};
    }

    // Depth-1 F double-buffer (static indices under full unroll).
    bf16x8 FA0[2], FA1[2], FB0[2], FB1[2];

    // ---- prologue: stage W(0) -> lds[0]; gather F(0) ----
    {
        float4 vw0 = *(const float4*)((const char*)wsw + s0);
        float4 vw1 = *(const float4*)((const char*)wsw + s1);
        const ushort* fa = fb + (size_t)ivA[0] * IN_CH + quad * 8;
        FA0[0] = *(const bf16x8*)fa;
        FA1[0] = *(const bf16x8*)(fa + 32);
        const ushort* fbp = fb + (size_t)ivB[0] * IN_CH + quad * 8;
        FB0[0] = *(const bf16x8*)fbp;
        FB1[0] = *(const bf16x8*)(fbp + 32);
        // Backend waits vmcnt only for vw here; F(0) stays in flight.
        *(float4*)(smraw + s0) = vw0;
        *(float4*)(smraw + s1) = vw1;
        asm volatile("s_waitcnt lgkmcnt(0)" ::: "memory");
        __builtin_amdgcn_s_barrier();
        __builtin_amdgcn_sched_barrier(0);
    }

#pragma unroll
    for (int k = 0; k < 9; ++k) {
        const int cur = k & 1;
        const int nxt = cur ^ 1;

        // 1. issue stage loads for W(k+1), then F(k+1) gathers (younger)
        float4 vw0, vw1;
        if (k < 8) {
            const char* src = (const char*)wsw + (size_t)(k + 1) * 16384;
            vw0 = *(const float4*)(src + s0);
            vw1 = *(const float4*)(src + s1);
            const ushort* fa = fb + (size_t)ivA[k + 1] * IN_CH + quad * 8;
            FA0[nxt] = *(const bf16x8*)fa;
            FA1[nxt] = *(const bf16x8*)(fa + 32);
            const ushort* fbp = fb + (size_t)ivB[k + 1] * IN_CH + quad * 8;
            FB0[nxt] = *(const bf16x8*)fbp;
            FB1[nxt] = *(const bf16x8*)(fbp + 32);
        }

        // 2. compute: W frags from lds[cur] (lgkm waits), F(k) landed
        const ushort* wl = &ldsW[cur][lane * 8];
#pragma unroll
        for (int g = 0; g < 8; ++g) {
            bf16x8 W0 = *(const bf16x8*)(wl + (g * 2 + 0) * 512);
            bf16x8 W1 = *(const bf16x8*)(wl + (g * 2 + 1) * 512);
            accA[g] = __builtin_amdgcn_mfma_f32_16x16x32_bf16(W0, FA0[cur], accA[g], 0, 0, 0);
            accA[g] = __builtin_amdgcn_mfma_f32_16x16x32_bf16(W1, FA1[cur], accA[g], 0, 0, 0);
            accB[g] = __builtin_amdgcn_mfma_f32_16x16x32_bf16(W0, FB0[cur], accB[g], 0, 0, 0);
            accB[g] = __builtin_amdgcn_mfma_f32_16x16x32_bf16(W1, FB1[cur], accB[g], 0, 0, 0);
        }

        // 3. commit stage to lds[nxt]; backend waits vmcnt only for vw,
        //    leaving F(k+1) in flight. lgkmcnt(0)+barrier publishes.
        if (k < 8) {
            char* dstb = smraw + nxt * 16384;
            *(float4*)(dstb + s0) = vw0;
            *(float4*)(dstb + s1) = vw1;
            asm volatile("s_waitcnt lgkmcnt(0)" ::: "memory");
            __builtin_amdgcn_s_barrier();
            __builtin_amdgcn_sched_barrier(0);
        }
    }

    // BN stats: sum over entries = butterfly over the 16 col-lanes (masks
    // 1..8 stay inside a quad). Invalid entries are exact zeros.
    f32x4 ss[8], qq[8];
#pragma unroll
    for (int g = 0; g < 8; ++g) {
        ss[g] = accA[g] + accB[g];
        qq[g] = accA[g] * accA[g] + accB[g] * accB[g];
    }
#pragma unroll
    for (int m = 1; m <= 8; m <<= 1) {
#pragma unroll
        for (int g = 0; g < 8; ++g) {
#pragma unroll
            for (int j = 0; j < 4; ++j) {
                ss[g][j] += __shfl_xor(ss[g][j], m);
                qq[g][j] += __shfl_xor(qq[g][j], m);
            }
        }
    }
    if (col == 0) {
#pragma unroll
        for (int g = 0; g < 8; ++g)
#pragma unroll
            for (int j = 0; j < 4; ++j) {
                redS[w * OUT_CH + g * 16 + quad * 4 + j] = ss[g][j];
                redQ[w * OUT_CH + g * 16 + quad * 4 + j] = qq[g][j];
            }
    }
    __syncthreads();
    if (threadIdx.x < OUT_CH) {
        int c = threadIdx.x;
        float a = 0.f, bq = 0.f;
#pragma unroll
        for (int r = 0; r < 8; ++r) {
            a  += redS[r * OUT_CH + c];
            bq += redQ[r * OUT_CH + c];
        }
        atomicAdd(&sums[c], a);
        atomicAdd(&sums[OUT_CH + c], bq);
    }
    __syncthreads();   // redS region about to be overwritten by transpose

    // Epilogue: coalesced out-store via LDS transpose. 4 passes; pass p:
    // waves 2p,2p+1 dump their 64 rows into [64][132]f buffer, then all
    // 512 threads stream 64x128 floats out as contiguous full-line bursts.
    float* buf = (float*)smraw;
    const int tid = threadIdx.x;
#pragma unroll
    for (int p = 0; p < 4; ++p) {
        if ((w >> 1) == p) {
            int rowA = ((w & 1) << 5) + col;
            int rowB = rowA + 16;
            float* bA = buf + rowA * 132 + quad * 4;
            float* bB = buf + rowB * 132 + quad * 4;
#pragma unroll
            for (int g = 0; g < 8; ++g) {
                *(f32x4*)(bA + g * 16) = accA[g];
                *(f32x4*)(bB + g * 16) = accB[g];
            }
        }
        __syncthreads();
        int gp = blockIdx.x * 256 + p * 64;
#pragma unroll
        for (int j = 0; j < 4; ++j) {
            int idx = j * 512 + tid;          // 0..2047
            int row = idx >> 5;               // 0..63
            int c4 = (idx & 31) * 4;
            int grow = gp + row;
            if (grow < n_out) {
                f32x4 v = *(const f32x4*)(buf + row * 132 + c4);
                *(f32x4*)(out + (size_t)grow * OUT_CH + c4) = v;
            }
        }
        __syncthreads();
    }
}

// y = gamma*(x-mean)*rsqrt(var+eps)+beta, relu; in-place, float4.
__global__ void __launch_bounds__(256) bn_relu_kernel(
    float4* __restrict__ out,
    const float* __restrict__ sums,
    const float* __restrict__ gamma,
    const float* __restrict__ beta,
    int total4, float inv_n)
{
    int idx = blockIdx.x * 256 + threadIdx.x;
    if (idx >= total4) return;
    int c0 = (idx & 31) * 4;
    float4 v = out[idx];
    float r[4] = {v.x, v.y, v.z, v.w};
#pragma unroll
    for (int j = 0; j < 4; ++j) {
        int c = c0 + j;
        float mean = sums[c] * inv_n;
        float var = sums[OUT_CH + c] * inv_n - mean * mean;
        float scale = gamma[c] * rsqrtf(var + 1e-5f);
        float y = (r[j] - mean) * scale + beta[c];
        r[j] = fmaxf(y, 0.0f);
    }
    out[idx] = make_float4(r[0], r[1], r[2], r[3]);
}

// ---------- fallback (atomic scatter) if ws too small ----------

__global__ void __launch_bounds__(256) zero_kernel(float4* __restrict__ out, int n4,
                                                   float* __restrict__ sums) {
    int idx = blockIdx.x * 256 + threadIdx.x;
    if (idx < n4) out[idx] = make_float4(0.f, 0.f, 0.f, 0.f);
    if (blockIdx.x == 0 && threadIdx.x < 2 * OUT_CH) sums[threadIdx.x] = 0.f;
}

__global__ void __launch_bounds__(256) scatter_gemm_kernel(
    const float* __restrict__ feats,
    const float* __restrict__ W,
    const int* __restrict__ in_idx,
    const int* __restrict__ out_idx,
    const int* __restrict__ mask,
    float* __restrict__ acc,
    int R)
{
    const int lane = threadIdx.x & 63;
    const int waveId = threadIdx.x >> 6;
    const int half = waveId & 1;
    const int pair = waveId >> 1;
    const int k = blockIdx.y;
    const int c = half * 64 + lane;

    float wreg[IN_CH];
    const float* __restrict__ wp = W + (size_t)k * IN_CH * OUT_CH + c;
#pragma unroll
    for (int i = 0; i < IN_CH; ++i) wreg[i] = wp[i * OUT_CH];

    const int r0 = blockIdx.x * 128;
    const int rEnd = min(r0 + 128, R);
    const int* __restrict__ maskK = mask + (size_t)k * R;
    const int* __restrict__ inK = in_idx + (size_t)k * R;
    const int* __restrict__ outK = out_idx + (size_t)k * R;

    for (int r = r0 + pair; r < rEnd; r += 2) {
        if (!__builtin_amdgcn_readfirstlane(maskK[r])) continue;
        int in = __builtin_amdgcn_readfirstlane(inK[r]);
        int out = __builtin_amdgcn_readfirstlane(outK[r]);
        const float* __restrict__ f = feats + (size_t)in * IN_CH;
        float s = 0.f, s1 = 0.f;
#pragma unroll
        for (int i = 0; i < IN_CH; i += 2) {
            s = fmaf(wreg[i], f[i], s);
            s1 = fmaf(wreg[i + 1], f[i + 1], s1);
        }
        atomicAdd(acc + (size_t)out * OUT_CH + c, s + s1);
    }
}

__global__ void __launch_bounds__(128) stats_kernel(
    const float* __restrict__ acc,
    float* __restrict__ sums,
    int n_out)
{
    int c = threadIdx.x;
    float s = 0.0f, s2 = 0.0f;
    for (int r = blockIdx.x; r < n_out; r += gridDim.x) {
        float v = acc[(size_t)r * OUT_CH + c];
        s += v;
        s2 += v * v;
    }
    atomicAdd(&sums[c], s);
    atomicAdd(&sums[OUT_CH + c], s2);
}

// ---------- launch ----------

extern "C" void kernel_launch(void* const* d_in, const int* in_sizes, int n_in,
                              void* d_out, int out_size, void* d_ws, size_t ws_size,
                              hipStream_t stream) {
    const float* feats   = (const float*)d_in[0];
    const float* W       = (const float*)d_in[1];
    const float* gamma   = (const float*)d_in[2];
    const float* beta    = (const float*)d_in[3];
    const int*   in_idx  = (const int*)d_in[4];
    const int*   out_idx = (const int*)d_in[5];
    const int*   mask    = (const int*)d_in[6];   // bool stored as int32

    const int R = in_sizes[4] / 9;
    const int n_out = out_size / OUT_CH;
    const int N_in = in_sizes[0] / IN_CH;
    float* acc = (float*)d_out;

    size_t off_inv  = 0;
    size_t sz_inv   = (size_t)n_out * 9 * sizeof(int);
    size_t off_sums = (off_inv + sz_inv + 15) & ~(size_t)15;
    size_t off_fb   = (off_sums + 1024 + 15) & ~(size_t)15;
    size_t off_wsw  = (off_fb + (size_t)(N_in + 1) * IN_CH * 2 + 15) & ~(size_t)15;
    size_t needed   = off_wsw + (size_t)9 * OUT_CH * IN_CH * 2;

    if (ws_size >= needed) {
        int*    inv  = (int*)((char*)d_ws + off_inv);
        float*  sums = (float*)((char*)d_ws + off_sums);
        ushort* fb   = (ushort*)((char*)d_ws + off_fb);
        ushort* wsw  = (ushort*)((char*)d_ws + off_wsw);

        const int invTot = n_out * 9;
        const int n4 = N_in * IN_CH / 4;
        const int invBlocks = (invTot + 255) / 256;
        const int cvtBlocks = (n4 + 16 + 255) / 256;
        const int wswBlocks = (9 * 16 * 64 + 255) / 256;

        prep_kernel<<<invBlocks + cvtBlocks + wswBlocks, 256, 0, stream>>>(
            inv, invTot, N_in, sums,
            (const float4*)feats, fb, n4,
            W, wsw, invBlocks, cvtBlocks);

        dim3 gridB((R + 255) / 256, 9);
        build_inv_kernel<<<gridB, 256, 0, stream>>>(in_idx, out_idx, mask, inv, R);

        fused_out_kernel<<<(n_out + 255) / 256, 512, 0, stream>>>(
            fb, wsw, inv, acc, sums, n_out, N_in);

        int total4 = out_size / 4;
        bn_relu_kernel<<<(total4 + 255) / 256, 256, 0, stream>>>(
            (float4*)acc, sums, gamma, beta, total4, 1.0f / (float)n_out);
    } else {
        float* sums = (float*)d_ws;
        int n4 = out_size / 4;
        zero_kernel<<<(n4 + 255) / 256, 256, 0, stream>>>((float4*)acc, n4, sums);

        dim3 grid((R + 127) / 128, 9);
        scatter_gemm_kernel<<<grid, 256, 0, stream>>>(feats, W, in_idx, out_idx, mask, acc, R);

        stats_kernel<<<2048, 128, 0, stream>>>(acc, sums, n_out);

        int total4 = out_size / 4;
        bn_relu_kernel<<<(total4 + 255) / 256, 256, 0, stream>>>(
            (float4*)acc, sums, gamma, beta, total4, 1.0f / (float)n_out);
    }
}

// Round 13
// 392.797 us; speedup vs baseline: 1.1010x; 1.1010x over previous
//
#include <hip/hip_runtime.h>
#include <hip/hip_bf16.h>
#include <stdint.h>

#define IN_CH 64
#define OUT_CH 128

typedef __bf16 bf16x8 __attribute__((ext_vector_type(8)));
typedef float  f32x4  __attribute__((ext_vector_type(4)));

__device__ inline unsigned short f2bf(float f) {
    unsigned u = __float_as_uint(f);
    unsigned r = (u + 0x7fffu + ((u >> 16) & 1u)) >> 16;
    return (unsigned short)r;
}

// ---------- fast path ----------

// One prep kernel, three block-ranges:
//  [0, invBlocks)                : inv[] = zero_row; sums = 0
//  [invBlocks, invBlocks+cvtB)   : feats fp32 -> bf16 (+1 zero row)
//  [invBlocks+cvtB, ...)         : W -> wsw, bf16 in MFMA-A fragment order:
//     wsw[((k*16 + g*2 + h)*64 + lane)*8 + j] = bf16(W[k][h*32+(lane>>4)*8+j][g*16+(lane&15)])
__global__ void __launch_bounds__(256) prep_kernel(
    int* __restrict__ inv, int invTot, int zero_row, float* __restrict__ sums,
    const float4* __restrict__ f4, ushort* __restrict__ fb, int n4,
    const float* __restrict__ W, ushort* __restrict__ wsw,
    int invBlocks, int cvtBlocks)
{
    const int b = blockIdx.x;
    const int t = threadIdx.x;
    if (b < invBlocks) {
        int i = b * 256 + t;
        if (i < invTot) inv[i] = zero_row;
        if (b == 0) sums[t] = 0.f;
    } else if (b < invBlocks + cvtBlocks) {
        int i = (b - invBlocks) * 256 + t;
        if (i < n4 + 16) {
            ushort4 o;
            if (i < n4) {
                float4 v = f4[i];
                o.x = f2bf(v.x); o.y = f2bf(v.y); o.z = f2bf(v.z); o.w = f2bf(v.w);
            } else {
                o.x = 0; o.y = 0; o.z = 0; o.w = 0;   // zero row for absent entries
            }
            ((ushort4*)fb)[i] = o;
        }
    } else {
        int i = (b - invBlocks - cvtBlocks) * 256 + t;  // one thread = one fragment chunk
        if (i < 9 * 16 * 64) {
            int lane = i & 63;
            int gh = (i >> 6) & 15;
            int k = i >> 10;
            int half = gh & 1;
            int g = gh >> 1;
            int ch = g * 16 + (lane & 15);
            int in0 = half * 32 + (lane >> 4) * 8;
            ushort v[8];
#pragma unroll
            for (int j = 0; j < 8; ++j)
                v[j] = f2bf(W[((size_t)k * IN_CH + in0 + j) * OUT_CH + ch]);
            *(ushort4*)(wsw + (size_t)i * 8)     = make_ushort4(v[0], v[1], v[2], v[3]);
            *(ushort4*)(wsw + (size_t)i * 8 + 4) = make_ushort4(v[4], v[5], v[6], v[7]);
        }
    }
}

// Inverse rulebook, atomic-free: for fixed k the in->out map of a strided
// conv is injective, so inv[out*9+k] has exactly one writer.
__global__ void __launch_bounds__(256) build_inv_kernel(
    const int* __restrict__ in_idx,
    const int* __restrict__ out_idx,
    const int* __restrict__ mask,
    int* __restrict__ inv,
    int R)
{
    int r = blockIdx.x * 256 + threadIdx.x;
    if (r >= R) return;
    int k = blockIdx.y;
    size_t e = (size_t)k * R + r;
    if (!mask[e]) return;
    inv[(size_t)out_idx[e] * 9 + k] = in_idx[e];
}

// Fused: out[e] = sum_k W[k]^T . fb[inv[e][k]], + fused BN-stat partials.
// 8 waves / 256 contiguous entries per block (locality load-bearing, r10).
// Verified r4/r8/r11 sync skeleton: W tiles reg-staged into 2x16KB LDS
// double-buffer, backend-managed vmcnt, raw s_barrier, depth-1 F prefetch.
// Staging is two lane-stride-16B streams (conflict-free; r11's 32B stride
// was a 1.68M-hit bank conflict, fixed r12). Epilogue = DIRECT stores:
// r12's LDS-transpose epilogue regressed (acc liveness across 8 barriers
// -> scratch round-trips, +120MB traffic). Direct stores retire acc
// immediately and L2 line-merges the 8 consecutive wave stores.
__global__ void __launch_bounds__(512, 3) fused_out_kernel(
    const ushort* __restrict__ fb,    // [N_in+1][64] bf16 (last row zeros)
    const ushort* __restrict__ wsw,   // [9][16][64][8] bf16 fragment-order
    const int* __restrict__ inv,      // [n_out][9]
    float* __restrict__ out,          // [n_out][128] fp32
    float* __restrict__ sums,         // [256]
    int n_out, int zero_row)
{
    __shared__ __align__(16) char smraw[40960];
    // [0,32768) = 2 x 16KB W tiles; [32768,40960) = redS/redQ
    ushort (*ldsW)[8192] = (ushort(*)[8192])smraw;
    float* redS = (float*)(smraw + 32768);            // [8][128]
    float* redQ = (float*)(smraw + 36864);            // [8][128]

    const int lane = threadIdx.x & 63;
    const int w = threadIdx.x >> 6;            // 0..7
    const int col = lane & 15;
    const int quad = lane >> 4;
    const int base = blockIdx.x * 256 + w * 32;
    const int eA = base + col;
    const int eB = base + 16 + col;
    const bool okA = eA < n_out;
    const bool okB = eB < n_out;

    int ivA[9], ivB[9];
    {
        const int* __restrict__ pA = inv + (size_t)(okA ? eA : 0) * 9;
        const int* __restrict__ pB = inv + (size_t)(okB ? eB : 0) * 9;
#pragma unroll
        for (int k = 0; k < 9; ++k) ivA[k] = okA ? pA[k] : zero_row;
#pragma unroll
        for (int k = 0; k < 9; ++k) ivB[k] = okB ? pB[k] : zero_row;
    }

    // Wave stages 2KB/tile as TWO lane-stride-16B streams (conflict-free).
    const int s0 = w * 2048 + lane * 16;       // first KB
    const int s1 = s0 + 1024;                  // second KB

    f32x4 accA[8], accB[8];
#pragma unroll
    for (int g = 0; g < 8; ++g) {
        accA[g] = (f32x4){0.f, 0.f, 0.f, 0.f};
        accB[g] = (f32x4){0.f, 0.f, 0.f, 0.f};
    }

    // Depth-1 F double-buffer (static indices under full unroll).
    bf16x8 FA0[2], FA1[2], FB0[2], FB1[2];

    // ---- prologue: stage W(0) -> lds[0]; gather F(0) ----
    {
        float4 vw0 = *(const float4*)((const char*)wsw + s0);
        float4 vw1 = *(const float4*)((const char*)wsw + s1);
        const ushort* fa = fb + (size_t)ivA[0] * IN_CH + quad * 8;
        FA0[0] = *(const bf16x8*)fa;
        FA1[0] = *(const bf16x8*)(fa + 32);
        const ushort* fbp = fb + (size_t)ivB[0] * IN_CH + quad * 8;
        FB0[0] = *(const bf16x8*)fbp;
        FB1[0] = *(const bf16x8*)(fbp + 32);
        // Backend waits vmcnt only for vw here; F(0) stays in flight.
        *(float4*)(smraw + s0) = vw0;
        *(float4*)(smraw + s1) = vw1;
        asm volatile("s_waitcnt lgkmcnt(0)" ::: "memory");
        __builtin_amdgcn_s_barrier();
        __builtin_amdgcn_sched_barrier(0);
    }

#pragma unroll
    for (int k = 0; k < 9; ++k) {
        const int cur = k & 1;
        const int nxt = cur ^ 1;

        // 1. issue stage loads for W(k+1), then F(k+1) gathers (younger)
        float4 vw0, vw1;
        if (k < 8) {
            const char* src = (const char*)wsw + (size_t)(k + 1) * 16384;
            vw0 = *(const float4*)(src + s0);
            vw1 = *(const float4*)(src + s1);
            const ushort* fa = fb + (size_t)ivA[k + 1] * IN_CH + quad * 8;
            FA0[nxt] = *(const bf16x8*)fa;
            FA1[nxt] = *(const bf16x8*)(fa + 32);
            const ushort* fbp = fb + (size_t)ivB[k + 1] * IN_CH + quad * 8;
            FB0[nxt] = *(const bf16x8*)fbp;
            FB1[nxt] = *(const bf16x8*)(fbp + 32);
        }

        // 2. compute: W frags from lds[cur] (lgkm waits), F(k) landed
        const ushort* wl = &ldsW[cur][lane * 8];
#pragma unroll
        for (int g = 0; g < 8; ++g) {
            bf16x8 W0 = *(const bf16x8*)(wl + (g * 2 + 0) * 512);
            bf16x8 W1 = *(const bf16x8*)(wl + (g * 2 + 1) * 512);
            accA[g] = __builtin_amdgcn_mfma_f32_16x16x32_bf16(W0, FA0[cur], accA[g], 0, 0, 0);
            accA[g] = __builtin_amdgcn_mfma_f32_16x16x32_bf16(W1, FA1[cur], accA[g], 0, 0, 0);
            accB[g] = __builtin_amdgcn_mfma_f32_16x16x32_bf16(W0, FB0[cur], accB[g], 0, 0, 0);
            accB[g] = __builtin_amdgcn_mfma_f32_16x16x32_bf16(W1, FB1[cur], accB[g], 0, 0, 0);
        }

        // 3. commit stage to lds[nxt]; backend waits vmcnt only for vw,
        //    leaving F(k+1) in flight. lgkmcnt(0)+barrier publishes.
        if (k < 8) {
            char* dstb = smraw + nxt * 16384;
            *(float4*)(dstb + s0) = vw0;
            *(float4*)(dstb + s1) = vw1;
            asm volatile("s_waitcnt lgkmcnt(0)" ::: "memory");
            __builtin_amdgcn_s_barrier();
            __builtin_amdgcn_sched_barrier(0);
        }
    }

    // Store: lane holds channels g*16 + quad*4 + {0..3} of its entry.
    // Direct stores retire acc immediately (no extended liveness).
    if (okA) {
        float* __restrict__ rp = out + (size_t)eA * OUT_CH + quad * 4;
#pragma unroll
        for (int g = 0; g < 8; ++g)
            *(f32x4*)(rp + g * 16) = accA[g];
    }
    if (okB) {
        float* __restrict__ rp = out + (size_t)eB * OUT_CH + quad * 4;
#pragma unroll
        for (int g = 0; g < 8; ++g)
            *(f32x4*)(rp + g * 16) = accB[g];
    }

    // BN stats: sum over entries = butterfly over the 16 col-lanes (masks
    // 1..8 stay inside a quad). Invalid entries are exact zeros.
    f32x4 ss[8], qq[8];
#pragma unroll
    for (int g = 0; g < 8; ++g) {
        ss[g] = accA[g] + accB[g];
        qq[g] = accA[g] * accA[g] + accB[g] * accB[g];
    }
#pragma unroll
    for (int m = 1; m <= 8; m <<= 1) {
#pragma unroll
        for (int g = 0; g < 8; ++g) {
#pragma unroll
            for (int j = 0; j < 4; ++j) {
                ss[g][j] += __shfl_xor(ss[g][j], m);
                qq[g][j] += __shfl_xor(qq[g][j], m);
            }
        }
    }
    if (col == 0) {
#pragma unroll
        for (int g = 0; g < 8; ++g)
#pragma unroll
            for (int j = 0; j < 4; ++j) {
                redS[w * OUT_CH + g * 16 + quad * 4 + j] = ss[g][j];
                redQ[w * OUT_CH + g * 16 + quad * 4 + j] = qq[g][j];
            }
    }
    __syncthreads();
    if (threadIdx.x < OUT_CH) {
        int c = threadIdx.x;
        float a = 0.f, bq = 0.f;
#pragma unroll
        for (int r = 0; r < 8; ++r) {
            a  += redS[r * OUT_CH + c];
            bq += redQ[r * OUT_CH + c];
        }
        atomicAdd(&sums[c], a);
        atomicAdd(&sums[OUT_CH + c], bq);
    }
}

// y = gamma*(x-mean)*rsqrt(var+eps)+beta, relu; in-place, float4.
__global__ void __launch_bounds__(256) bn_relu_kernel(
    float4* __restrict__ out,
    const float* __restrict__ sums,
    const float* __restrict__ gamma,
    const float* __restrict__ beta,
    int total4, float inv_n)
{
    int idx = blockIdx.x * 256 + threadIdx.x;
    if (idx >= total4) return;
    int c0 = (idx & 31) * 4;
    float4 v = out[idx];
    float r[4] = {v.x, v.y, v.z, v.w};
#pragma unroll
    for (int j = 0; j < 4; ++j) {
        int c = c0 + j;
        float mean = sums[c] * inv_n;
        float var = sums[OUT_CH + c] * inv_n - mean * mean;
        float scale = gamma[c] * rsqrtf(var + 1e-5f);
        float y = (r[j] - mean) * scale + beta[c];
        r[j] = fmaxf(y, 0.0f);
    }
    out[idx] = make_float4(r[0], r[1], r[2], r[3]);
}

// ---------- fallback (atomic scatter) if ws too small ----------

__global__ void __launch_bounds__(256) zero_kernel(float4* __restrict__ out, int n4,
                                                   float* __restrict__ sums) {
    int idx = blockIdx.x * 256 + threadIdx.x;
    if (idx < n4) out[idx] = make_float4(0.f, 0.f, 0.f, 0.f);
    if (blockIdx.x == 0 && threadIdx.x < 2 * OUT_CH) sums[threadIdx.x] = 0.f;
}

__global__ void __launch_bounds__(256) scatter_gemm_kernel(
    const float* __restrict__ feats,
    const float* __restrict__ W,
    const int* __restrict__ in_idx,
    const int* __restrict__ out_idx,
    const int* __restrict__ mask,
    float* __restrict__ acc,
    int R)
{
    const int lane = threadIdx.x & 63;
    const int waveId = threadIdx.x >> 6;
    const int half = waveId & 1;
    const int pair = waveId >> 1;
    const int k = blockIdx.y;
    const int c = half * 64 + lane;

    float wreg[IN_CH];
    const float* __restrict__ wp = W + (size_t)k * IN_CH * OUT_CH + c;
#pragma unroll
    for (int i = 0; i < IN_CH; ++i) wreg[i] = wp[i * OUT_CH];

    const int r0 = blockIdx.x * 128;
    const int rEnd = min(r0 + 128, R);
    const int* __restrict__ maskK = mask + (size_t)k * R;
    const int* __restrict__ inK = in_idx + (size_t)k * R;
    const int* __restrict__ outK = out_idx + (size_t)k * R;

    for (int r = r0 + pair; r < rEnd; r += 2) {
        if (!__builtin_amdgcn_readfirstlane(maskK[r])) continue;
        int in = __builtin_amdgcn_readfirstlane(inK[r]);
        int out = __builtin_amdgcn_readfirstlane(outK[r]);
        const float* __restrict__ f = feats + (size_t)in * IN_CH;
        float s = 0.f, s1 = 0.f;
#pragma unroll
        for (int i = 0; i < IN_CH; i += 2) {
            s = fmaf(wreg[i], f[i], s);
            s1 = fmaf(wreg[i + 1], f[i + 1], s1);
        }
        atomicAdd(acc + (size_t)out * OUT_CH + c, s + s1);
    }
}

__global__ void __launch_bounds__(128) stats_kernel(
    const float* __restrict__ acc,
    float* __restrict__ sums,
    int n_out)
{
    int c = threadIdx.x;
    float s = 0.0f, s2 = 0.0f;
    for (int r = blockIdx.x; r < n_out; r += gridDim.x) {
        float v = acc[(size_t)r * OUT_CH + c];
        s += v;
        s2 += v * v;
    }
    atomicAdd(&sums[c], s);
    atomicAdd(&sums[OUT_CH + c], s2);
}

// ---------- launch ----------

extern "C" void kernel_launch(void* const* d_in, const int* in_sizes, int n_in,
                              void* d_out, int out_size, void* d_ws, size_t ws_size,
                              hipStream_t stream) {
    const float* feats   = (const float*)d_in[0];
    const float* W       = (const float*)d_in[1];
    const float* gamma   = (const float*)d_in[2];
    const float* beta    = (const float*)d_in[3];
    const int*   in_idx  = (const int*)d_in[4];
    const int*   out_idx = (const int*)d_in[5];
    const int*   mask    = (const int*)d_in[6];   // bool stored as int32

    const int R = in_sizes[4] / 9;
    const int n_out = out_size / OUT_CH;
    const int N_in = in_sizes[0] / IN_CH;
    float* acc = (float*)d_out;

    size_t off_inv  = 0;
    size_t sz_inv   = (size_t)n_out * 9 * sizeof(int);
    size_t off_sums = (off_inv + sz_inv + 15) & ~(size_t)15;
    size_t off_fb   = (off_sums + 1024 + 15) & ~(size_t)15;
    size_t off_wsw  = (off_fb + (size_t)(N_in + 1) * IN_CH * 2 + 15) & ~(size_t)15;
    size_t needed   = off_wsw + (size_t)9 * OUT_CH * IN_CH * 2;

    if (ws_size >= needed) {
        int*    inv  = (int*)((char*)d_ws + off_inv);
        float*  sums = (float*)((char*)d_ws + off_sums);
        ushort* fb   = (ushort*)((char*)d_ws + off_fb);
        ushort* wsw  = (ushort*)((char*)d_ws + off_wsw);

        const int invTot = n_out * 9;
        const int n4 = N_in * IN_CH / 4;
        const int invBlocks = (invTot + 255) / 256;
        const int cvtBlocks = (n4 + 16 + 255) / 256;
        const int wswBlocks = (9 * 16 * 64 + 255) / 256;

        prep_kernel<<<invBlocks + cvtBlocks + wswBlocks, 256, 0, stream>>>(
            inv, invTot, N_in, sums,
            (const float4*)feats, fb, n4,
            W, wsw, invBlocks, cvtBlocks);

        dim3 gridB((R + 255) / 256, 9);
        build_inv_kernel<<<gridB, 256, 0, stream>>>(in_idx, out_idx, mask, inv, R);

        fused_out_kernel<<<(n_out + 255) / 256, 512, 0, stream>>>(
            fb, wsw, inv, acc, sums, n_out, N_in);

        int total4 = out_size / 4;
        bn_relu_kernel<<<(total4 + 255) / 256, 256, 0, stream>>>(
            (float4*)acc, sums, gamma, beta, total4, 1.0f / (float)n_out);
    } else {
        float* sums = (float*)d_ws;
        int n4 = out_size / 4;
        zero_kernel<<<(n4 + 255) / 256, 256, 0, stream>>>((float4*)acc, n4, sums);

        dim3 grid((R + 127) / 128, 9);
        scatter_gemm_kernel<<<grid, 256, 0, stream>>>(feats, W, in_idx, out_idx, mask, acc, R);

        stats_kernel<<<2048, 128, 0, stream>>>(acc, sums, n_out);

        int total4 = out_size / 4;
        bn_relu_kernel<<<(total4 + 255) / 256, 256, 0, stream>>>(
            (float4*)acc, sums, gamma, beta, total4, 1.0f / (float)n_out);
    }
}